// Round 2
// baseline (168.575 us; speedup 1.0000x reference)
//
#include <hip/hip_runtime.h>

#define BATCH 4096
#define SEQT  512
#define HID   32

typedef _Float16 f16;
typedef _Float16 h2 __attribute__((ext_vector_type(2)));

#if __has_builtin(__builtin_amdgcn_fdot2)
#define FDOT2(a, b, c) __builtin_amdgcn_fdot2((a), (b), (c), false)
#else
#define FDOT2(a, b, c) fmaf((float)(a)[1], (float)(b)[1], fmaf((float)(a)[0], (float)(b)[0], (c)))
#endif

#if __has_builtin(__builtin_amdgcn_exp2f)
#define FAST_EXP2(x) __builtin_amdgcn_exp2f(x)
#else
#define FAST_EXP2(x) exp2f(x)
#endif
#if __has_builtin(__builtin_amdgcn_rcpf)
#define FAST_RCP(x) __builtin_amdgcn_rcpf(x)
#else
#define FAST_RCP(x) (1.0f / (x))
#endif

// DPP lane-xor controls (all stay within a 16-lane row => within a seq group)
#define DPP_X1  0xB1   // quad_perm [1,0,3,2] : lane ^= 1
#define DPP_X2  0x4E   // quad_perm [2,3,0,1] : lane ^= 2
#define DPP_X7  0x141  // row_half_mirror     : lane ^= 7
#define DPP_X15 0x140  // row_mirror          : lane ^= 15

#if __has_builtin(__builtin_amdgcn_update_dpp)
template <int C, typename T>
__device__ __forceinline__ T xl(T v) {
    return __builtin_bit_cast(T, __builtin_amdgcn_update_dpp(
        0, __builtin_bit_cast(int, v), C, 0xF, 0xF, false));
}
#else
template <int C, typename T>
__device__ __forceinline__ T xl(T v) {
    constexpr int m = (C == DPP_X1) ? 1 : (C == DPP_X2) ? 2 : (C == DPP_X7) ? 7 : 15;
    return __builtin_bit_cast(T, __shfl_xor(__builtin_bit_cast(int, v), m));
}
#endif

// 16 lanes per sequence; lane ell owns h-pair (h[2*ell], h[2*ell+1]) as one h2.
// Per step: 15 DPP movs all-gather the 16 pairs into regs (reg r holds pair
// ell ^ MTBL[r]; W_hh regs are permuted per-lane at init to match), then
// 32 fdot2 compute the two output rows, tanh, repack. NO LDS, no barriers,
// no waitcnt in the recurrence. Output dot: 1 fdot2 partial + 4-round DPP
// butterfly-add; lane ell retains timestep (t mod 16)==ell, coalesced store
// per 16-step half-chunk. x is register-resident, prefetched one half ahead.
__global__ __launch_bounds__(256) void rnn_kernel(
    const float* __restrict__ x,      // [B, T]
    const float* __restrict__ h0,     // [B, H]
    const float* __restrict__ W_ih,   // [H]
    const float* __restrict__ b_ih,   // [H]
    const float* __restrict__ W_hh,   // [H, H] row-major
    const float* __restrict__ b_hh,   // [H]
    const float* __restrict__ W_out,  // [H]
    const float* __restrict__ b_out,  // [1]
    float* __restrict__ out)          // [B*T] outs, then [B*H] hT
{
    const int tid  = threadIdx.x;
    const int ell  = tid & 15;                       // lane within seq group
    const int bseq = (blockIdx.x * 256 + tid) >> 4;  // sequence index
    const int j0 = 2 * ell, j1 = 2 * ell + 1;        // owned output rows

    // gather-reg r holds pair (ell ^ MTBL[r]) after the DPP rounds below
    constexpr int MTBL[16] = {0, 1, 2, 3, 7, 6, 5, 4, 15, 14, 13, 12, 8, 9, 10, 11};

    // ---- W_hh rows j0/j1 packed f16, permuted to match gather order ----
    h2 W0[16], W1[16];
    #pragma unroll
    for (int r = 0; r < 16; ++r) {
        const int p = ell ^ MTBL[r];
        const float2 w0 = *reinterpret_cast<const float2*>(W_hh + j0 * HID + 2 * p);
        const float2 w1 = *reinterpret_cast<const float2*>(W_hh + j1 * HID + 2 * p);
        W0[r] = h2{(f16)w0.x, (f16)w0.y};
        W1[r] = h2{(f16)w1.x, (f16)w1.y};
    }
    const float2 wo = *reinterpret_cast<const float2*>(W_out + j0);
    const h2 Wo2 = h2{(f16)wo.x, (f16)wo.y};
    const float wih0 = W_ih[j0], wih1 = W_ih[j1];
    const float bia0 = b_ih[j0] + b_hh[j0];
    const float bia1 = b_ih[j1] + b_hh[j1];
    const float bout = b_out[0];

    // seed h_{-1}
    const float2 h0v = *reinterpret_cast<const float2*>(h0 + (size_t)bseq * HID + j0);
    h2 hcur = h2{(f16)h0v.x, (f16)h0v.y};
    float hn0 = h0v.x, hn1 = h0v.y;

    const float* xg = x + (size_t)bseq * SEQT;
    float*       og = out + (size_t)bseq * SEQT;

#define STEP(T2, XC) do {                                                     \
    h2 v0 = hcur;                                                             \
    h2 v1 = xl<DPP_X1>(v0);                                                   \
    h2 v2 = xl<DPP_X2>(v0);                                                   \
    h2 v3 = xl<DPP_X2>(v1);                                                   \
    h2 v4 = xl<DPP_X7>(v0);                                                   \
    h2 v5 = xl<DPP_X7>(v1);                                                   \
    h2 v6 = xl<DPP_X7>(v2);                                                   \
    h2 v7 = xl<DPP_X7>(v3);                                                   \
    h2 v8  = xl<DPP_X15>(v0);                                                 \
    h2 v9  = xl<DPP_X15>(v1);                                                 \
    h2 v10 = xl<DPP_X15>(v2);                                                 \
    h2 v11 = xl<DPP_X15>(v3);                                                 \
    h2 v12 = xl<DPP_X15>(v4);                                                 \
    h2 v13 = xl<DPP_X15>(v5);                                                 \
    h2 v14 = xl<DPP_X15>(v6);                                                 \
    h2 v15 = xl<DPP_X15>(v7);                                                 \
    float a0 = fmaf((XC), wih0, bia0);                                        \
    float b0 = fmaf((XC), wih1, bia1);                                        \
    a0 = FDOT2(v0,  W0[0],  a0);                                              \
    float a1 = FDOT2(v1,  W0[1],  0.0f);                                      \
    float a2 = FDOT2(v2,  W0[2],  0.0f);                                      \
    float a3 = FDOT2(v3,  W0[3],  0.0f);                                      \
    a0 = FDOT2(v4,  W0[4],  a0); a1 = FDOT2(v5,  W0[5],  a1);                 \
    a2 = FDOT2(v6,  W0[6],  a2); a3 = FDOT2(v7,  W0[7],  a3);                 \
    a0 = FDOT2(v8,  W0[8],  a0); a1 = FDOT2(v9,  W0[9],  a1);                 \
    a2 = FDOT2(v10, W0[10], a2); a3 = FDOT2(v11, W0[11], a3);                 \
    a0 = FDOT2(v12, W0[12], a0); a1 = FDOT2(v13, W0[13], a1);                 \
    a2 = FDOT2(v14, W0[14], a2); a3 = FDOT2(v15, W0[15], a3);                 \
    b0 = FDOT2(v0,  W1[0],  b0);                                              \
    float b1 = FDOT2(v1,  W1[1],  0.0f);                                      \
    float b2 = FDOT2(v2,  W1[2],  0.0f);                                      \
    float b3 = FDOT2(v3,  W1[3],  0.0f);                                      \
    b0 = FDOT2(v4,  W1[4],  b0); b1 = FDOT2(v5,  W1[5],  b1);                 \
    b2 = FDOT2(v6,  W1[6],  b2); b3 = FDOT2(v7,  W1[7],  b3);                 \
    b0 = FDOT2(v8,  W1[8],  b0); b1 = FDOT2(v9,  W1[9],  b1);                 \
    b2 = FDOT2(v10, W1[10], b2); b3 = FDOT2(v11, W1[11], b3);                 \
    b0 = FDOT2(v12, W1[12], b0); b1 = FDOT2(v13, W1[13], b1);                 \
    b2 = FDOT2(v14, W1[14], b2); b3 = FDOT2(v15, W1[15], b3);                 \
    const float s0 = (a0 + a1) + (a2 + a3);                                   \
    const float s1 = (b0 + b1) + (b2 + b3);                                   \
    const float e0 = FAST_EXP2(s0 * 2.8853900817779268f);                     \
    const float e1 = FAST_EXP2(s1 * 2.8853900817779268f);                     \
    hn0 = fmaf(-2.0f, FAST_RCP(e0 + 1.0f), 1.0f);                             \
    hn1 = fmaf(-2.0f, FAST_RCP(e1 + 1.0f), 1.0f);                             \
    hcur = h2{(f16)hn0, (f16)hn1};                                            \
    float pp = FDOT2(hcur, Wo2, 0.0f);                                        \
    pp += xl<DPP_X1>(pp);                                                     \
    pp += xl<DPP_X2>(pp);                                                     \
    pp += xl<DPP_X7>(pp);                                                     \
    pp += xl<DPP_X15>(pp);                                                    \
    if (ell == (T2)) osel = pp;                                               \
} while (0)

#define HALF(HC, Q0, Q1, Q2, Q3) do {                                         \
    float osel = 0.0f;                                                        \
    STEP(0,  (Q0).x); STEP(1,  (Q0).y); STEP(2,  (Q0).z); STEP(3,  (Q0).w);   \
    STEP(4,  (Q1).x); STEP(5,  (Q1).y); STEP(6,  (Q1).z); STEP(7,  (Q1).w);   \
    STEP(8,  (Q2).x); STEP(9,  (Q2).y); STEP(10, (Q2).z); STEP(11, (Q2).w);   \
    STEP(12, (Q3).x); STEP(13, (Q3).y); STEP(14, (Q3).z); STEP(15, (Q3).w);   \
    og[(HC) * 16 + ell] = osel + bout;                                        \
} while (0)

    // x register double-buffer: 16 steps (4x float4) per half-chunk
    const float4* xq0 = reinterpret_cast<const float4*>(xg);
    float4 qA0 = xq0[0], qA1 = xq0[1], qA2 = xq0[2], qA3 = xq0[3];
    float4 qB0, qB1, qB2, qB3;

    #pragma unroll 1
    for (int hc = 0; hc < 32; hc += 2) {
        const float4* pB = reinterpret_cast<const float4*>(xg + (hc + 1) * 16);
        qB0 = pB[0]; qB1 = pB[1]; qB2 = pB[2]; qB3 = pB[3];
        HALF(hc, qA0, qA1, qA2, qA3);
        const int tn = (hc + 2 < 32) ? (hc + 2) : 0;  // clamp: harmless reload
        const float4* pA = reinterpret_cast<const float4*>(xg + tn * 16);
        qA0 = pA[0]; qA1 = pA[1]; qA2 = pA[2]; qA3 = pA[3];
        HALF(hc + 1, qB0, qB1, qB2, qB3);
    }

    // final hidden state [1, B, H] (f32 pre-rounding values, as before)
    float2 ht; ht.x = hn0; ht.y = hn1;
    *reinterpret_cast<float2*>(out + (size_t)BATCH * SEQT + (size_t)bseq * HID + j0) = ht;

#undef HALF
#undef STEP
}

extern "C" void kernel_launch(void* const* d_in, const int* in_sizes, int n_in,
                              void* d_out, int out_size, void* d_ws, size_t ws_size,
                              hipStream_t stream) {
    const float* x     = (const float*)d_in[0];
    const float* h0    = (const float*)d_in[1];
    const float* W_ih  = (const float*)d_in[2];
    const float* b_ih  = (const float*)d_in[3];
    const float* W_hh  = (const float*)d_in[4];
    const float* b_hh  = (const float*)d_in[5];
    const float* W_out = (const float*)d_in[6];
    const float* b_out = (const float*)d_in[7];
    float* outp = (float*)d_out;

    dim3 grid(BATCH * 16 / 256);   // 256 blocks x 4 waves x 4 seqs/wave
    dim3 block(256);
    hipLaunchKernelGGL(rnn_kernel, grid, block, 0, stream,
                       x, h0, W_ih, b_ih, W_hh, b_hh, W_out, b_out, outp);
}

// Round 3
// 160.945 us; speedup vs baseline: 1.0474x; 1.0474x over previous
//
#include <hip/hip_runtime.h>

#define BATCH 4096
#define SEQT  512
#define HID   32

typedef _Float16 f16;
typedef _Float16 h2 __attribute__((ext_vector_type(2)));

#if __has_builtin(__builtin_amdgcn_fdot2)
#define FDOT2(a, b, c) __builtin_amdgcn_fdot2((a), (b), (c), false)
#else
#define FDOT2(a, b, c) fmaf((float)(a)[1], (float)(b)[1], fmaf((float)(a)[0], (float)(b)[0], (c)))
#endif

#if __has_builtin(__builtin_amdgcn_exp2f)
#define FAST_EXP2(x) __builtin_amdgcn_exp2f(x)
#else
#define FAST_EXP2(x) exp2f(x)
#endif
#if __has_builtin(__builtin_amdgcn_rcpf)
#define FAST_RCP(x) __builtin_amdgcn_rcpf(x)
#else
#define FAST_RCP(x) (1.0f / (x))
#endif

// DPP lane-xor controls (all stay within a 16-lane row => within a seq group)
#define DPP_X1  0xB1   // quad_perm [1,0,3,2] : lane ^= 1
#define DPP_X2  0x4E   // quad_perm [2,3,0,1] : lane ^= 2
#define DPP_X7  0x141  // row_half_mirror     : lane ^= 7
#define DPP_X15 0x140  // row_mirror          : lane ^= 15

// Prefer mov_dpp (no tied 'old' operand -> single v_mov_b32_dpp, no zero-init
// mov per shuffle). update_dpp(0,..) forces the allocator to materialize the
// old value: ~19 extra v_movs per timestep.
#if __has_builtin(__builtin_amdgcn_mov_dpp)
template <int C, typename T>
__device__ __forceinline__ T xl(T v) {
    return __builtin_bit_cast(T, __builtin_amdgcn_mov_dpp(
        __builtin_bit_cast(int, v), C, 0xF, 0xF, false));
}
#elif __has_builtin(__builtin_amdgcn_update_dpp)
template <int C, typename T>
__device__ __forceinline__ T xl(T v) {
    return __builtin_bit_cast(T, __builtin_amdgcn_update_dpp(
        0, __builtin_bit_cast(int, v), C, 0xF, 0xF, false));
}
#else
template <int C, typename T>
__device__ __forceinline__ T xl(T v) {
    constexpr int m = (C == DPP_X1) ? 1 : (C == DPP_X2) ? 2 : (C == DPP_X7) ? 7 : 15;
    return __builtin_bit_cast(T, __shfl_xor(__builtin_bit_cast(int, v), m));
}
#endif

// 16 lanes per sequence; lane ell owns h-pair (h[2*ell], h[2*ell+1]) as one h2.
// Per step: 15 DPP movs all-gather the 16 pairs into regs (reg r holds pair
// ell ^ MTBL[r]; W_hh regs are permuted per-lane at init to match), then
// 32 fdot2 compute the two output rows, tanh, repack. NO LDS, no barriers,
// no waitcnt in the recurrence. Output dot: 1 fdot2 partial + 4-round DPP
// butterfly-add; lane ell retains timestep (t mod 16)==ell, coalesced store
// per 16-step half-chunk. x is register-resident, prefetched one half ahead.
//
// __launch_bounds__(256, 1): grid supplies exactly 1 wave/SIMD (1024 waves on
// 1024 SIMDs) -- cap the allocator at 1 wave/EU so it may use the full VGPR
// file. Round-2 showed 84 VGPRs (occupancy-targeted) -> live-range splits +
// x re-loads -> ~190 inst/step instead of ~80.
__global__ __launch_bounds__(256, 1) void rnn_kernel(
    const float* __restrict__ x,      // [B, T]
    const float* __restrict__ h0,     // [B, H]
    const float* __restrict__ W_ih,   // [H]
    const float* __restrict__ b_ih,   // [H]
    const float* __restrict__ W_hh,   // [H, H] row-major
    const float* __restrict__ b_hh,   // [H]
    const float* __restrict__ W_out,  // [H]
    const float* __restrict__ b_out,  // [1]
    float* __restrict__ out)          // [B*T] outs, then [B*H] hT
{
    const int tid  = threadIdx.x;
    const int ell  = tid & 15;                       // lane within seq group
    const int bseq = (blockIdx.x * 256 + tid) >> 4;  // sequence index
    const int j0 = 2 * ell, j1 = 2 * ell + 1;        // owned output rows

    // gather-reg r holds pair (ell ^ MTBL[r]) after the DPP rounds below
    constexpr int MTBL[16] = {0, 1, 2, 3, 7, 6, 5, 4, 15, 14, 13, 12, 8, 9, 10, 11};

    // ---- W_hh rows j0/j1 packed f16, permuted to match gather order ----
    h2 W0[16], W1[16];
    #pragma unroll
    for (int r = 0; r < 16; ++r) {
        const int p = ell ^ MTBL[r];
        const float2 w0 = *reinterpret_cast<const float2*>(W_hh + j0 * HID + 2 * p);
        const float2 w1 = *reinterpret_cast<const float2*>(W_hh + j1 * HID + 2 * p);
        W0[r] = h2{(f16)w0.x, (f16)w0.y};
        W1[r] = h2{(f16)w1.x, (f16)w1.y};
    }
    const float2 wo = *reinterpret_cast<const float2*>(W_out + j0);
    const h2 Wo2 = h2{(f16)wo.x, (f16)wo.y};
    const float wih0 = W_ih[j0], wih1 = W_ih[j1];
    const float bia0 = b_ih[j0] + b_hh[j0];
    const float bia1 = b_ih[j1] + b_hh[j1];
    const float bout = b_out[0];

    // seed h_{-1}
    const float2 h0v = *reinterpret_cast<const float2*>(h0 + (size_t)bseq * HID + j0);
    h2 hcur = h2{(f16)h0v.x, (f16)h0v.y};
    float hn0 = h0v.x, hn1 = h0v.y;

    const float* xg = x + (size_t)bseq * SEQT;
    float*       og = out + (size_t)bseq * SEQT;

#define STEP(T2, XC) do {                                                     \
    h2 v0 = hcur;                                                             \
    h2 v1 = xl<DPP_X1>(v0);                                                   \
    h2 v2 = xl<DPP_X2>(v0);                                                   \
    h2 v3 = xl<DPP_X2>(v1);                                                   \
    h2 v4 = xl<DPP_X7>(v0);                                                   \
    h2 v5 = xl<DPP_X7>(v1);                                                   \
    h2 v6 = xl<DPP_X7>(v2);                                                   \
    h2 v7 = xl<DPP_X7>(v3);                                                   \
    h2 v8  = xl<DPP_X15>(v0);                                                 \
    h2 v9  = xl<DPP_X15>(v1);                                                 \
    h2 v10 = xl<DPP_X15>(v2);                                                 \
    h2 v11 = xl<DPP_X15>(v3);                                                 \
    h2 v12 = xl<DPP_X15>(v4);                                                 \
    h2 v13 = xl<DPP_X15>(v5);                                                 \
    h2 v14 = xl<DPP_X15>(v6);                                                 \
    h2 v15 = xl<DPP_X15>(v7);                                                 \
    float a0 = fmaf((XC), wih0, bia0);                                        \
    float b0 = fmaf((XC), wih1, bia1);                                        \
    a0 = FDOT2(v0,  W0[0],  a0);                                              \
    float a1 = FDOT2(v1,  W0[1],  0.0f);                                      \
    float a2 = FDOT2(v2,  W0[2],  0.0f);                                      \
    float a3 = FDOT2(v3,  W0[3],  0.0f);                                      \
    a0 = FDOT2(v4,  W0[4],  a0); a1 = FDOT2(v5,  W0[5],  a1);                 \
    a2 = FDOT2(v6,  W0[6],  a2); a3 = FDOT2(v7,  W0[7],  a3);                 \
    a0 = FDOT2(v8,  W0[8],  a0); a1 = FDOT2(v9,  W0[9],  a1);                 \
    a2 = FDOT2(v10, W0[10], a2); a3 = FDOT2(v11, W0[11], a3);                 \
    a0 = FDOT2(v12, W0[12], a0); a1 = FDOT2(v13, W0[13], a1);                 \
    a2 = FDOT2(v14, W0[14], a2); a3 = FDOT2(v15, W0[15], a3);                 \
    b0 = FDOT2(v0,  W1[0],  b0);                                              \
    float b1 = FDOT2(v1,  W1[1],  0.0f);                                      \
    float b2 = FDOT2(v2,  W1[2],  0.0f);                                      \
    float b3 = FDOT2(v3,  W1[3],  0.0f);                                      \
    b0 = FDOT2(v4,  W1[4],  b0); b1 = FDOT2(v5,  W1[5],  b1);                 \
    b2 = FDOT2(v6,  W1[6],  b2); b3 = FDOT2(v7,  W1[7],  b3);                 \
    b0 = FDOT2(v8,  W1[8],  b0); b1 = FDOT2(v9,  W1[9],  b1);                 \
    b2 = FDOT2(v10, W1[10], b2); b3 = FDOT2(v11, W1[11], b3);                 \
    b0 = FDOT2(v12, W1[12], b0); b1 = FDOT2(v13, W1[13], b1);                 \
    b2 = FDOT2(v14, W1[14], b2); b3 = FDOT2(v15, W1[15], b3);                 \
    const float s0 = (a0 + a1) + (a2 + a3);                                   \
    const float s1 = (b0 + b1) + (b2 + b3);                                   \
    const float e0 = FAST_EXP2(s0 * 2.8853900817779268f);                     \
    const float e1 = FAST_EXP2(s1 * 2.8853900817779268f);                     \
    hn0 = fmaf(-2.0f, FAST_RCP(e0 + 1.0f), 1.0f);                             \
    hn1 = fmaf(-2.0f, FAST_RCP(e1 + 1.0f), 1.0f);                             \
    hcur = h2{(f16)hn0, (f16)hn1};                                            \
    float pp = FDOT2(hcur, Wo2, 0.0f);                                        \
    pp += xl<DPP_X1>(pp);                                                     \
    pp += xl<DPP_X2>(pp);                                                     \
    pp += xl<DPP_X7>(pp);                                                     \
    pp += xl<DPP_X15>(pp);                                                    \
    if (ell == (T2)) osel = pp;                                               \
} while (0)

#define HALF(HC, Q0, Q1, Q2, Q3) do {                                         \
    float osel = 0.0f;                                                        \
    STEP(0,  (Q0).x); STEP(1,  (Q0).y); STEP(2,  (Q0).z); STEP(3,  (Q0).w);   \
    STEP(4,  (Q1).x); STEP(5,  (Q1).y); STEP(6,  (Q1).z); STEP(7,  (Q1).w);   \
    STEP(8,  (Q2).x); STEP(9,  (Q2).y); STEP(10, (Q2).z); STEP(11, (Q2).w);   \
    STEP(12, (Q3).x); STEP(13, (Q3).y); STEP(14, (Q3).z); STEP(15, (Q3).w);   \
    og[(HC) * 16 + ell] = osel + bout;                                        \
} while (0)

    // x register double-buffer: 16 steps (4x float4) per half-chunk
    const float4* xq0 = reinterpret_cast<const float4*>(xg);
    float4 qA0 = xq0[0], qA1 = xq0[1], qA2 = xq0[2], qA3 = xq0[3];
    float4 qB0, qB1, qB2, qB3;

    #pragma unroll 1
    for (int hc = 0; hc < 32; hc += 2) {
        const float4* pB = reinterpret_cast<const float4*>(xg + (hc + 1) * 16);
        qB0 = pB[0]; qB1 = pB[1]; qB2 = pB[2]; qB3 = pB[3];
        HALF(hc, qA0, qA1, qA2, qA3);
        const int tn = (hc + 2 < 32) ? (hc + 2) : 0;  // clamp: harmless reload
        const float4* pA = reinterpret_cast<const float4*>(xg + tn * 16);
        qA0 = pA[0]; qA1 = pA[1]; qA2 = pA[2]; qA3 = pA[3];
        HALF(hc + 1, qB0, qB1, qB2, qB3);
    }

    // final hidden state [1, B, H] (f32 pre-rounding values, as before)
    float2 ht; ht.x = hn0; ht.y = hn1;
    *reinterpret_cast<float2*>(out + (size_t)BATCH * SEQT + (size_t)bseq * HID + j0) = ht;

#undef HALF
#undef STEP
}

extern "C" void kernel_launch(void* const* d_in, const int* in_sizes, int n_in,
                              void* d_out, int out_size, void* d_ws, size_t ws_size,
                              hipStream_t stream) {
    const float* x     = (const float*)d_in[0];
    const float* h0    = (const float*)d_in[1];
    const float* W_ih  = (const float*)d_in[2];
    const float* b_ih  = (const float*)d_in[3];
    const float* W_hh  = (const float*)d_in[4];
    const float* b_hh  = (const float*)d_in[5];
    const float* W_out = (const float*)d_in[6];
    const float* b_out = (const float*)d_in[7];
    float* outp = (float*)d_out;

    dim3 grid(BATCH * 16 / 256);   // 256 blocks x 4 waves x 4 seqs/wave
    dim3 block(256);
    hipLaunchKernelGGL(rnn_kernel, grid, block, 0, stream,
                       x, h0, W_ih, b_ih, W_hh, b_hh, W_out, b_out, outp);
}